// Round 1
// baseline (86.307 us; speedup 1.0000x reference)
//
#include <hip/hip_runtime.h>

#define F 32
#define D_HALF 256

__global__ __launch_bounds__(256) void pe_kernel(const float* __restrict__ x,
                                                 float2* __restrict__ out) {
    const int b = blockIdx.x;
    const int j = threadIdx.x;  // 0..255

    __shared__ float xs[F];
    if (threadIdx.x < F) xs[threadIdx.x] = x[b * F + threadIdx.x];
    __syncthreads();

    // div_term[j] = 10000^(-j/256); fold 1/(2*pi) in so the angle is in
    // revolutions for the raw v_sin/v_cos instructions.
    // drev = exp2(-j*log2(10000)/256 - log2(2*pi))
    const float kExp = -0.051905126482615036f;  // -log2(10000)/256
    const float kOff = -2.651496129472319f;     // -log2(2*pi)
    const float drev = __builtin_amdgcn_exp2f(fmaf((float)j, kExp, kOff));

    float sacc = 0.0f, cacc = 0.0f;
#pragma unroll
    for (int f = 0; f < F; ++f) {
        float a = xs[f] * drev;          // angle in revolutions
        a = __builtin_amdgcn_fractf(a);  // safe range reduction for v_sin/v_cos
        sacc += __builtin_amdgcn_sinf(a);
        cacc += __builtin_amdgcn_cosf(a);
    }

    // out[b, 2j] = sin_mean, out[b, 2j+1] = cos_mean  -> one coalesced float2
    out[b * D_HALF + j] = make_float2(sacc * (1.0f / F), cacc * (1.0f / F));
}

extern "C" void kernel_launch(void* const* d_in, const int* in_sizes, int n_in,
                              void* d_out, int out_size, void* d_ws, size_t ws_size,
                              hipStream_t stream) {
    const float* x = (const float*)d_in[0];
    float2* out = (float2*)d_out;
    const int B = in_sizes[0] / F;  // 16384
    pe_kernel<<<B, 256, 0, stream>>>(x, out);
}

// Round 2
// 71.338 us; speedup vs baseline: 1.2098x; 1.2098x over previous
//
#include <hip/hip_runtime.h>

#define F 32
#define D_HALF 256
#define NP 22        // powers x^1 .. x^22
#define STRIDE 23    // odd stride -> conflict-free LDS

// kTable[p-1] = sign_p / (p! * 32); sin: p odd, sign (-1)^((p-1)/2); cos: p even, sign (-1)^(p/2)
__constant__ float kTable[NP] = {
     3.125e-2f,                // p=1   +1/(1!*32)
    -1.5625e-2f,               // p=2   -1/(2!*32)
    -5.2083333333333336e-3f,   // p=3
     1.3020833333333333e-3f,   // p=4
     2.6041666666666666e-4f,   // p=5
    -4.3402777777777778e-5f,   // p=6
    -6.2003968253968254e-6f,   // p=7
     7.7504960317460317e-7f,   // p=8
     8.6116622574955908e-8f,   // p=9
    -8.6116622574955908e-9f,   // p=10
    -7.8287838704505371e-10f,  // p=11
     6.5239865587087809e-11f,  // p=12
     5.0184511989929083e-12f,  // p=13
    -3.5846079992806488e-13f,  // p=14
    -2.3897386661870992e-14f,  // p=15
     1.4935866663669370e-15f,  // p=16
     8.7858039198055118e-17f,  // p=17
    -4.8810021776697288e-18f,  // p=18
    -2.5689485145630152e-19f,  // p=19
     1.2844742572815076e-20f,  // p=20
     6.1165440822928934e-22f,  // p=21
    -2.7802473101331334e-23f   // p=22
};

__global__ __launch_bounds__(256) void pe_kernel(const float* __restrict__ x,
                                                 float2* __restrict__ out) {
    const int b = blockIdx.x;
    const int tid = threadIdx.x;

    __shared__ float pw[F * STRIDE];
    __shared__ float mom[NP];   // mom[p-1] = sign_p/(p!) * mean_f(x^p)

    // Phase 1: lanes 0..31 compute powers of their sample into LDS.
    if (tid < F) {
        const float v = x[b * F + tid];
        float p = v;
#pragma unroll
        for (int k = 0; k < NP; ++k) {
            pw[tid * STRIDE + k] = p;
            p *= v;
        }
    }
    __syncthreads();

    // Phase 2: lanes 0..21 reduce across the 32 samples, scale by sign/(p!*32).
    if (tid < NP) {
        float s = 0.0f;
#pragma unroll
        for (int f = 0; f < F; ++f) s += pw[f * STRIDE + tid];
        mom[tid] = s * kTable[tid];
    }
    __syncthreads();

    // Phase 3: thread j evaluates both Taylor series via Horner in t = d^2.
    const float kExp = -0.05190512648261503f;  // -log2(10000)/256
    const float d = __builtin_amdgcn_exp2f((float)tid * kExp);
    const float t = d * d;

    // sin_mean = d*(A1 + t*(A3 + ... + t*A21)), A_p = mom[p-1]
    float s = mom[20];
    s = fmaf(s, t, mom[18]);
    s = fmaf(s, t, mom[16]);
    s = fmaf(s, t, mom[14]);
    s = fmaf(s, t, mom[12]);
    s = fmaf(s, t, mom[10]);
    s = fmaf(s, t, mom[8]);
    s = fmaf(s, t, mom[6]);
    s = fmaf(s, t, mom[4]);
    s = fmaf(s, t, mom[2]);
    s = fmaf(s, t, mom[0]);
    s *= d;

    // cos_mean = 1 + t*(A2 + t*(A4 + ... + t*A22))
    float c = mom[21];
    c = fmaf(c, t, mom[19]);
    c = fmaf(c, t, mom[17]);
    c = fmaf(c, t, mom[15]);
    c = fmaf(c, t, mom[13]);
    c = fmaf(c, t, mom[11]);
    c = fmaf(c, t, mom[9]);
    c = fmaf(c, t, mom[7]);
    c = fmaf(c, t, mom[5]);
    c = fmaf(c, t, mom[3]);
    c = fmaf(c, t, mom[1]);
    c = fmaf(c, t, 1.0f);

    out[b * D_HALF + tid] = make_float2(s, c);
}

extern "C" void kernel_launch(void* const* d_in, const int* in_sizes, int n_in,
                              void* d_out, int out_size, void* d_ws, size_t ws_size,
                              hipStream_t stream) {
    const float* x = (const float*)d_in[0];
    float2* out = (float2*)d_out;
    const int B = in_sizes[0] / F;  // 16384
    pe_kernel<<<B, 256, 0, stream>>>(x, out);
}